// Round 3
// baseline (234.343 us; speedup 1.0000x reference)
//
#include <hip/hip_runtime.h>

typedef __attribute__((ext_vector_type(8))) short short8;
typedef __attribute__((ext_vector_type(4))) float f32x4;

typedef const __attribute__((address_space(1))) unsigned int as1_u32;
typedef __attribute__((address_space(3))) unsigned int as3_u32;

#define E2f   7.38905609893065f     // exp(2)
#define OSCALE 1.69864357f          // sqrt(2*log2(e)) ; dot of scaled rows = 2*log2(e)*dot

#define EXP2(x) exp2f(x)

__device__ inline unsigned short f2bf(float f){
    union { float f; unsigned int u; } x; x.f = f;
    unsigned int u = x.u;
    return (unsigned short)((u + 0x7fffu + ((u >> 16) & 1u)) >> 16);
}

__device__ inline short8 pack8(float4 a, float4 b){
    short8 t;
    t[0]=(short)f2bf(a.x); t[1]=(short)f2bf(a.y); t[2]=(short)f2bf(a.z); t[3]=(short)f2bf(a.w);
    t[4]=(short)f2bf(b.x); t[5]=(short)f2bf(b.y); t[6]=(short)f2bf(b.z); t[7]=(short)f2bf(b.w);
    return t;
}

// ---- K0: cast+transpose W1 (512x128 -> 128x512 bf16) and W2 (128x128 -> 128x128 bf16)
__global__ __launch_bounds__(256) void k_prep(const float* __restrict__ W1, const float* __restrict__ W2,
                                              short* __restrict__ W1T, short* __restrict__ W2T){
    int idx = blockIdx.x*256 + threadIdx.x;
    if(idx < 512*128){
        int n = idx >> 9, k = idx & 511;
        W1T[idx] = (short)f2bf(W1[k*128 + n]);
    } else {
        int i2 = idx - 512*128;   // < 128*128
        int n = i2 >> 7, k = i2 & 127;
        W2T[i2] = (short)f2bf(W2[k*128 + n]);
    }
}

// ---- K1: h = doc @ W1 + b1. 1024 single-wave blocks (16 rows each) for occupancy.
__global__ __launch_bounds__(64) void k_gemm1(const float* __restrict__ doc, const float* __restrict__ b1,
                                              const short* __restrict__ W1T, float* __restrict__ h,
                                              float* __restrict__ bsum, float* __restrict__ bsq){
    int bid = blockIdx.x;
    int l = threadIdx.x, lr = l & 15, lk = l >> 4;
    int rowA = bid*16 + lr;

    short8 a[16];
    const float* dp = doc + rowA*512 + lk*8;
    #pragma unroll
    for(int c=0;c<16;c++){
        float4 f0 = *(const float4*)(dp + c*32);
        float4 f1 = *(const float4*)(dp + c*32 + 4);
        a[c] = pack8(f0, f1);
    }

    f32x4 acc[8];
    #pragma unroll
    for(int ct=0; ct<8; ct++) acc[ct] = (f32x4){0.f,0.f,0.f,0.f};

    const short* wb = W1T + lr*512 + lk*8;
    #pragma unroll
    for(int c=0;c<16;c++){
        #pragma unroll
        for(int ct=0; ct<8; ct++){
            short8 b = *(const short8*)(wb + ct*8192 + c*32);
            acc[ct] = __builtin_amdgcn_mfma_f32_16x16x32_bf16(a[c], b, acc[ct], 0,0,0);
        }
    }

    int rowD = bid*16 + lk*4;
    #pragma unroll
    for(int ct=0; ct<8; ct++){
        float bb = b1[ct*16 + lr];
        float s = 0.f, q = 0.f;
        #pragma unroll
        for(int r=0;r<4;r++){
            float v = acc[ct][r] + bb;
            h[(rowD + r)*128 + ct*16 + lr] = v;
            s += v; q += v*v;
        }
        s += __shfl_xor(s,16); s += __shfl_xor(s,32);
        q += __shfl_xor(q,16); q += __shfl_xor(q,32);
        if(lk==0){ bsum[bid*128 + ct*16 + lr] = s; bsq[bid*128 + ct*16 + lr] = q; }
    }
}

// ---- K2: finalize BN params (1024 block partials)
__global__ __launch_bounds__(512) void k_bnfin(const float* __restrict__ bsum, const float* __restrict__ bsq,
                                               const float* __restrict__ gamma, const float* __restrict__ beta,
                                               float* __restrict__ bnA, float* __restrict__ bnB){
    int tid = threadIdx.x;
    int c = tid & 127, seg = tid >> 7;
    float S=0.f, Q=0.f;
    for(int b=seg*256; b<seg*256+256; b++){ S += bsum[b*128+c]; Q += bsq[b*128+c]; }
    __shared__ float ls[4][128], lq[4][128];
    ls[seg][c] = S; lq[seg][c] = Q;
    __syncthreads();
    if(tid < 128){
        float St = ls[0][tid]+ls[1][tid]+ls[2][tid]+ls[3][tid];
        float Qt = lq[0][tid]+lq[1][tid]+lq[2][tid]+lq[3][tid];
        float mu = St * (1.0f/16384.0f);
        float var = Qt * (1.0f/16384.0f) - mu*mu;
        float A = gamma[tid] * rsqrtf(var + 1e-5f);
        bnA[tid] = A;
        bnB[tid] = beta[tid] - mu*A;
    }
}

// ---- K3: BN+ReLU -> GEMM2 -> +b2 -> L2 normalize -> pair dots -> scaled bf16. 1024x64.
__global__ __launch_bounds__(64) void k_gemm2(const float* __restrict__ h, const short* __restrict__ W2T,
                                              const float* __restrict__ bnA, const float* __restrict__ bnB,
                                              const float* __restrict__ b2,
                                              short* __restrict__ o1s, short* __restrict__ o2s,
                                              float* __restrict__ dvec){
    int bid = blockIdx.x;
    int l = threadIdx.x, lr = l & 15, lk = l >> 4;
    int rowA = bid*16 + lr;

    short8 a[4];
    const float* hp = h + rowA*128 + lk*8;
    #pragma unroll
    for(int c=0;c<4;c++){
        float4 h0 = *(const float4*)(hp + c*32);
        float4 h1 = *(const float4*)(hp + c*32 + 4);
        float4 A0 = *(const float4*)(bnA + c*32 + lk*8);
        float4 A1 = *(const float4*)(bnA + c*32 + lk*8 + 4);
        float4 B0 = *(const float4*)(bnB + c*32 + lk*8);
        float4 B1 = *(const float4*)(bnB + c*32 + lk*8 + 4);
        float4 v0, v1;
        v0.x = fmaxf(h0.x*A0.x + B0.x, 0.f); v0.y = fmaxf(h0.y*A0.y + B0.y, 0.f);
        v0.z = fmaxf(h0.z*A0.z + B0.z, 0.f); v0.w = fmaxf(h0.w*A0.w + B0.w, 0.f);
        v1.x = fmaxf(h1.x*A1.x + B1.x, 0.f); v1.y = fmaxf(h1.y*A1.y + B1.y, 0.f);
        v1.z = fmaxf(h1.z*A1.z + B1.z, 0.f); v1.w = fmaxf(h1.w*A1.w + B1.w, 0.f);
        a[c] = pack8(v0, v1);
    }

    f32x4 acc[8];
    #pragma unroll
    for(int ct=0; ct<8; ct++) acc[ct] = (f32x4){0.f,0.f,0.f,0.f};
    const short* wb = W2T + lr*128 + lk*8;
    #pragma unroll
    for(int c=0;c<4;c++){
        #pragma unroll
        for(int ct=0; ct<8; ct++){
            short8 b = *(const short8*)(wb + ct*2048 + c*32);
            acc[ct] = __builtin_amdgcn_mfma_f32_16x16x32_bf16(a[c], b, acc[ct], 0,0,0);
        }
    }

    #pragma unroll
    for(int ct=0; ct<8; ct++){
        float bb = b2[ct*16 + lr];
        #pragma unroll
        for(int r=0;r<4;r++) acc[ct][r] += bb;
    }
    float n2[4] = {0.f,0.f,0.f,0.f};
    #pragma unroll
    for(int ct=0; ct<8; ct++){
        #pragma unroll
        for(int r=0;r<4;r++) n2[r] += acc[ct][r]*acc[ct][r];
    }
    #pragma unroll
    for(int r=0;r<4;r++){
        n2[r] += __shfl_xor(n2[r],1); n2[r] += __shfl_xor(n2[r],2);
        n2[r] += __shfl_xor(n2[r],4); n2[r] += __shfl_xor(n2[r],8);
    }
    float sc[4];
    #pragma unroll
    for(int r=0;r<4;r++) sc[r] = 1.0f / fmaxf(sqrtf(n2[r]), 1e-12f);
    #pragma unroll
    for(int ct=0; ct<8; ct++){
        #pragma unroll
        for(int r=0;r<4;r++) acc[ct][r] *= sc[r];
    }
    float dp0 = 0.f, dp1 = 0.f;
    #pragma unroll
    for(int ct=0; ct<8; ct++){
        dp0 += acc[ct][0]*acc[ct][1];
        dp1 += acc[ct][2]*acc[ct][3];
    }
    dp0 += __shfl_xor(dp0,1); dp0 += __shfl_xor(dp0,2); dp0 += __shfl_xor(dp0,4); dp0 += __shfl_xor(dp0,8);
    dp1 += __shfl_xor(dp1,1); dp1 += __shfl_xor(dp1,2); dp1 += __shfl_xor(dp1,4); dp1 += __shfl_xor(dp1,8);
    int r0 = bid*16 + lk*4;
    if(lr==0){
        dvec[(r0>>1)    ] = dp0;
        dvec[(r0>>1) + 1] = dp1;
    }
    #pragma unroll
    for(int ct=0; ct<8; ct++){
        #pragma unroll
        for(int r=0;r<4;r++){
            int grow = r0 + r;
            int col  = ct*16 + lr;
            short bits = (short)f2bf(acc[ct][r] * OSCALE);
            if(grow & 1) o1s[(grow>>1)*128 + col] = bits;
            else         o2s[(grow>>1)*128 + col] = bits;
        }
    }
}

// ---- K4: fused similarity. grid (64, 16, 3).
//  z=0: S11 (sym, tiles by>=bx>>2), z=1: S22 (sym), z=2: S12 (full, colsum=S21 rowsums)
//  rowsum partials  -> r??p[by][row]
//  colsum partials  -> c??p[bx][col] (zero-filled for diag/skipped tiles of sym passes)
__global__ __launch_bounds__(256) void k_sim(const short* __restrict__ o1s, const short* __restrict__ o2s,
                                             float* __restrict__ r11p, float* __restrict__ r22p,
                                             float* __restrict__ r12p, float* __restrict__ c11p,
                                             float* __restrict__ c22p, float* __restrict__ c12p){
    int bx = blockIdx.x, by = blockIdx.y, pz = blockIdx.z;
    const short* A = (pz==1) ? o2s : o1s;
    const short* B = (pz==0) ? o1s : o2s;
    float* rowp = (pz==0) ? r11p : (pz==1 ? r22p : r12p);
    float* colp = (pz==0) ? c11p : (pz==1 ? c22p : c12p);

    int tid = threadIdx.x;
    int byd = bx >> 2;
    bool sym = (pz < 2);
    if(sym && by < byd){
        // zero-fill skipped slices (ws is poisoned, all slots must be written)
        if(tid < 128) rowp[by*8192 + bx*128 + tid] = 0.f;
        colp[bx*8192 + by*512 + tid] = 0.f;
        colp[bx*8192 + by*512 + 256 + tid] = 0.f;
        return;
    }
    bool do_col = (pz==2) || (by > byd);
    if(!do_col){
        colp[bx*8192 + by*512 + tid] = 0.f;
        colp[bx*8192 + by*512 + 256 + tid] = 0.f;
    }

    int w = tid>>6, l = tid&63, lr = l&15, lk = l>>4;

    __shared__ __align__(16) short lds[2][8192];   // 2 x (64 rows x 128 bf16) = 32KB exactly

    // A fragments: rows bx*128 + w*32 + rt*16 + lr
    short8 a[2][4];
    {
        const short* ap = A + (bx*128 + w*32 + lr)*128 + lk*8;
        #pragma unroll
        for(int rt=0;rt<2;rt++)
            #pragma unroll
            for(int c=0;c<4;c++)
                a[rt][c] = *(const short8*)(ap + rt*2048 + c*32);
    }

    // swizzled ds_read byte offsets per k-chunk c
    int sb[4];
    #pragma unroll
    for(int c=0;c<4;c++) sb[c] = lr*256 + ((((c*4+lk) ^ (lr&7)))<<4);

    // staging source pointers; col16 pre-swizzled so linear gload_lds dest gives
    // LDS[row][s] = B[row][s ^ (row&7)]
    const short* gsrc[4];
    #pragma unroll
    for(int i=0;i<4;i++){
        int row = (i*4 + w)*4 + (l>>4);
        int col16 = (l&15) ^ (row&7);
        gsrc[i] = B + (by*512 + row)*128 + col16*8;
    }

    // stage tile 0
    #pragma unroll
    for(int i=0;i<4;i++){
        __builtin_amdgcn_global_load_lds((as1_u32*)gsrc[i],
            (as3_u32*)(&lds[0][(i*4+w)*512]), 16, 0, 0);
        gsrc[i] += 8192;
    }

    float rs[2][4] = {{0.f,0.f,0.f,0.f},{0.f,0.f,0.f,0.f}};
    float cs8[8];
    int buf = 0;
    const char* lbase = (const char*)&lds[0][0];

    for(int t=0;t<8;t++){
        if(t<7){
            #pragma unroll
            for(int i=0;i<4;i++){
                __builtin_amdgcn_global_load_lds((as1_u32*)gsrc[i],
                    (as3_u32*)(&lds[buf^1][(i*4+w)*512]), 16, 0, 0);
                gsrc[i] += 8192;
            }
            asm volatile("s_waitcnt vmcnt(4)" ::: "memory");   // tile t landed; t+1 in flight
        } else {
            asm volatile("s_waitcnt vmcnt(0)" ::: "memory");
        }
        __builtin_amdgcn_s_barrier();                          // B1: tile t visible

        const char* lb = lbase + buf*16384;
        float cst = 0.f;
        #pragma unroll
        for(int jt=0;jt<4;jt++){
            short8 b0 = *(const short8*)(lb + jt*4096 + sb[0]);
            short8 b1 = *(const short8*)(lb + jt*4096 + sb[1]);
            short8 b2 = *(const short8*)(lb + jt*4096 + sb[2]);
            short8 b3 = *(const short8*)(lb + jt*4096 + sb[3]);
            f32x4 c0 = (f32x4){0.f,0.f,0.f,0.f};
            f32x4 c1 = (f32x4){0.f,0.f,0.f,0.f};
            c0 = __builtin_amdgcn_mfma_f32_16x16x32_bf16(a[0][0], b0, c0,0,0,0);
            c1 = __builtin_amdgcn_mfma_f32_16x16x32_bf16(a[1][0], b0, c1,0,0,0);
            c0 = __builtin_amdgcn_mfma_f32_16x16x32_bf16(a[0][1], b1, c0,0,0,0);
            c1 = __builtin_amdgcn_mfma_f32_16x16x32_bf16(a[1][1], b1, c1,0,0,0);
            c0 = __builtin_amdgcn_mfma_f32_16x16x32_bf16(a[0][2], b2, c0,0,0,0);
            c1 = __builtin_amdgcn_mfma_f32_16x16x32_bf16(a[1][2], b2, c1,0,0,0);
            c0 = __builtin_amdgcn_mfma_f32_16x16x32_bf16(a[0][3], b3, c0,0,0,0);
            c1 = __builtin_amdgcn_mfma_f32_16x16x32_bf16(a[1][3], b3, c1,0,0,0);
            float e00 = EXP2(c0[0]), e01 = EXP2(c0[1]), e02 = EXP2(c0[2]), e03 = EXP2(c0[3]);
            float e10 = EXP2(c1[0]), e11 = EXP2(c1[1]), e12 = EXP2(c1[2]), e13 = EXP2(c1[3]);
            rs[0][0]+=e00; rs[0][1]+=e01; rs[0][2]+=e02; rs[0][3]+=e03;
            rs[1][0]+=e10; rs[1][1]+=e11; rs[1][2]+=e12; rs[1][3]+=e13;
            // column partial (sum over this lane's 8 rows, then over lk groups);
            // lane keeps the jt==lk column slice -> 8 VGPRs total across t
            float cv = ((e00+e01)+(e02+e03)) + ((e10+e11)+(e12+e13));
            cv += __shfl_xor(cv,16); cv += __shfl_xor(cv,32);
            if(jt == lk) cst = cv;
        }
        cs8[t] = cst;
        __builtin_amdgcn_s_barrier();                          // B2: all done reading buf
        buf ^= 1;
    }

    // rowsum: reduce over 16 j-lanes, store per-split partial
    #pragma unroll
    for(int rt=0;rt<2;rt++){
        #pragma unroll
        for(int r=0;r<4;r++){
            rs[rt][r] += __shfl_xor(rs[rt][r],1);
            rs[rt][r] += __shfl_xor(rs[rt][r],2);
            rs[rt][r] += __shfl_xor(rs[rt][r],4);
            rs[rt][r] += __shfl_xor(rs[rt][r],8);
        }
        if(lr==0){
            float4 v; v.x=rs[rt][0]; v.y=rs[rt][1]; v.z=rs[rt][2]; v.w=rs[rt][3];
            *(float4*)(rowp + by*8192 + bx*128 + w*32 + rt*16 + lk*4) = v;
        }
    }

    // colsum epilogue: cross-wave reduce through (now dead) B-tile LDS
    if(do_col){
        float* lf = (float*)&lds[0][0];
        #pragma unroll
        for(int t=0;t<8;t++) lf[w*512 + t*64 + l] = cs8[t];   // j = t*64 + lk*16 + lr
        __syncthreads();
        int j0 = tid, j1 = tid + 256;
        float v0 = lf[j0] + lf[512+j0] + lf[1024+j0] + lf[1536+j0];
        float v1 = lf[j1] + lf[512+j1] + lf[1024+j1] + lf[1536+j1];
        colp[bx*8192 + by*512 + j0] = v0;
        colp[bx*8192 + by*512 + j1] = v1;
    }
}

// ---- K5: per-pair loss + block partial sums
__global__ __launch_bounds__(256) void k_loss1(const float* __restrict__ r11, const float* __restrict__ r22,
                                               const float* __restrict__ r12, const float* __restrict__ c11,
                                               const float* __restrict__ c22, const float* __restrict__ c12,
                                               const float* __restrict__ dvec, float* __restrict__ lpart){
    int i = blockIdx.x*256 + threadIdx.x;
    float s11=0.f, s12=0.f, s22=0.f, s21=0.f;
    #pragma unroll
    for(int s=0;s<16;s++){
        s11 += r11[s*8192+i]; s22 += r22[s*8192+i]; s12 += r12[s*8192+i];
    }
    #pragma unroll
    for(int s=0;s<64;s++){
        s11 += c11[s*8192+i]; s22 += c22[s*8192+i]; s21 += c12[s*8192+i];
    }
    float d1 = s11 - E2f + s12;
    float d2 = s22 - E2f + s21;
    float loss = 0.5f*(logf(d1)+logf(d2)) - 2.0f*dvec[i];
    loss += __shfl_xor(loss,1);  loss += __shfl_xor(loss,2);  loss += __shfl_xor(loss,4);
    loss += __shfl_xor(loss,8);  loss += __shfl_xor(loss,16); loss += __shfl_xor(loss,32);
    __shared__ float lds[4];
    if((threadIdx.x & 63) == 0) lds[threadIdx.x >> 6] = loss;
    __syncthreads();
    if(threadIdx.x == 0) lpart[blockIdx.x] = lds[0]+lds[1]+lds[2]+lds[3];
}

__global__ __launch_bounds__(64) void k_loss2(const float* __restrict__ lpart, float* __restrict__ out){
    if(threadIdx.x == 0){
        float s = 0.f;
        for(int i=0;i<32;i++) s += lpart[i];
        out[0] = s * (1.0f/8192.0f);
    }
}

extern "C" void kernel_launch(void* const* d_in, const int* in_sizes, int n_in,
                              void* d_out, int out_size, void* d_ws, size_t ws_size,
                              hipStream_t stream){
    (void)in_sizes; (void)n_in; (void)out_size; (void)ws_size;
    const float* doc   = (const float*)d_in[0];
    const float* W1    = (const float*)d_in[1];
    const float* b1    = (const float*)d_in[2];
    const float* gamma = (const float*)d_in[3];
    const float* beta  = (const float*)d_in[4];
    const float* W2    = (const float*)d_in[5];
    const float* b2    = (const float*)d_in[6];
    float* out = (float*)d_out;

    char* ws = (char*)d_ws;
    // [0, 8MB): h (live gemm1..gemm2), then reused by k_sim partials
    float* h     = (float*)(ws + 0);            // 16384*128*4 = 8388608
    float* c11p  = (float*)(ws + 0);            // 64*8192*4 = 2097152
    float* c22p  = (float*)(ws + 2097152);      // 2097152
    float* c12p  = (float*)(ws + 4194304);      // 2097152
    float* r11p  = (float*)(ws + 6291456);      // 16*8192*4 = 524288
    float* r22p  = (float*)(ws + 6815744);      // 524288
    float* r12p  = (float*)(ws + 7340032);      // 524288
    short* W1T   = (short*)(ws + 8388608);      // 131072
    short* W2T   = (short*)(ws + 8519680);      // 32768
    short* o1s   = (short*)(ws + 8552448);      // 2097152
    short* o2s   = (short*)(ws + 10649600);     // 2097152
    float* dvec  = (float*)(ws + 12746752);     // 32768
    float* bnA   = (float*)(ws + 12779520);     // 512
    float* bnB   = (float*)(ws + 12780032);     // 512
    float* bsum  = (float*)(ws + 12780544);     // 1024*128*4 = 524288
    float* bsq   = (float*)(ws + 13304832);     // 524288
    float* lpart = (float*)(ws + 13829120);     // 128

    k_prep <<<320, 256, 0, stream>>>(W1, W2, W1T, W2T);
    k_gemm1<<<1024, 64, 0, stream>>>(doc, b1, W1T, h, bsum, bsq);
    k_bnfin<<<1, 512, 0, stream>>>(bsum, bsq, gamma, beta, bnA, bnB);
    k_gemm2<<<1024, 64, 0, stream>>>(h, W2T, bnA, bnB, b2, o1s, o2s, dvec);
    dim3 sg(64, 16, 3);
    k_sim  <<<sg, 256, 0, stream>>>(o1s, o2s, r11p, r22p, r12p, c11p, c22p, c12p);
    k_loss1<<<32, 256, 0, stream>>>(r11p, r22p, r12p, c11p, c22p, c12p, dvec, lpart);
    k_loss2<<<1, 64, 0, stream>>>(lpart, out);
}

// Round 4
// 217.159 us; speedup vs baseline: 1.0791x; 1.0791x over previous
//
#include <hip/hip_runtime.h>

typedef __attribute__((ext_vector_type(8))) short short8;
typedef __attribute__((ext_vector_type(4))) float f32x4;

typedef const __attribute__((address_space(1))) unsigned int as1_u32;
typedef __attribute__((address_space(3))) unsigned int as3_u32;

#define E2f   7.38905609893065f     // exp(2)
#define OSCALE 1.69864357f          // sqrt(2*log2(e)) ; dot of scaled rows = 2*log2(e)*dot

#define EXP2(x) exp2f(x)

__device__ inline unsigned short f2bf(float f){
    union { float f; unsigned int u; } x; x.f = f;
    unsigned int u = x.u;
    return (unsigned short)((u + 0x7fffu + ((u >> 16) & 1u)) >> 16);
}

__device__ inline short8 pack8(float4 a, float4 b){
    short8 t;
    t[0]=(short)f2bf(a.x); t[1]=(short)f2bf(a.y); t[2]=(short)f2bf(a.z); t[3]=(short)f2bf(a.w);
    t[4]=(short)f2bf(b.x); t[5]=(short)f2bf(b.y); t[6]=(short)f2bf(b.z); t[7]=(short)f2bf(b.w);
    return t;
}

// ---- K0: cast+transpose W1 (512x128 -> 128x512 bf16) and W2 (128x128 -> 128x128 bf16)
__global__ __launch_bounds__(256) void k_prep(const float* __restrict__ W1, const float* __restrict__ W2,
                                              short* __restrict__ W1T, short* __restrict__ W2T){
    int idx = blockIdx.x*256 + threadIdx.x;
    if(idx < 512*128){
        int n = idx >> 9, k = idx & 511;
        W1T[idx] = (short)f2bf(W1[k*128 + n]);
    } else {
        int i2 = idx - 512*128;   // < 128*128
        int n = i2 >> 7, k = i2 & 127;
        W2T[i2] = (short)f2bf(W2[k*128 + n]);
    }
}

// ---- K1: h = doc @ W1 + b1 (bf16 MFMA), plus per-block BN partial sums (round-2 form)
__global__ __launch_bounds__(256) void k_gemm1(const float* __restrict__ doc, const float* __restrict__ b1,
                                               const short* __restrict__ W1T, float* __restrict__ h,
                                               float* __restrict__ bsum, float* __restrict__ bsq){
    int bid = blockIdx.x;                   // 256 blocks, 64 rows each
    int tid = threadIdx.x;
    int w = tid >> 6, l = tid & 63, lr = l & 15, lk = l >> 4;
    int rowA = bid*64 + w*16 + lr;

    short8 a[16];
    const float* dp = doc + rowA*512 + lk*8;
    #pragma unroll
    for(int c=0;c<16;c++){
        float4 f0 = *(const float4*)(dp + c*32);
        float4 f1 = *(const float4*)(dp + c*32 + 4);
        a[c] = pack8(f0, f1);
    }

    f32x4 acc[8];
    #pragma unroll
    for(int ct=0; ct<8; ct++) acc[ct] = (f32x4){0.f,0.f,0.f,0.f};

    const short* wb = W1T + lr*512 + lk*8;
    #pragma unroll
    for(int c=0;c<16;c++){
        #pragma unroll
        for(int ct=0; ct<8; ct++){
            short8 b = *(const short8*)(wb + ct*16*512 + c*32);
            acc[ct] = __builtin_amdgcn_mfma_f32_16x16x32_bf16(a[c], b, acc[ct], 0,0,0);
        }
    }

    __shared__ float lds_s[4][128];
    __shared__ float lds_q[4][128];
    int rowD = bid*64 + w*16 + lk*4;
    #pragma unroll
    for(int ct=0; ct<8; ct++){
        float bb = b1[ct*16 + lr];
        float s = 0.f, q = 0.f;
        #pragma unroll
        for(int r=0;r<4;r++){
            float v = acc[ct][r] + bb;
            h[(rowD + r)*128 + ct*16 + lr] = v;
            s += v; q += v*v;
        }
        s += __shfl_xor(s,16); s += __shfl_xor(s,32);
        q += __shfl_xor(q,16); q += __shfl_xor(q,32);
        if(lk==0){ lds_s[w][ct*16+lr] = s; lds_q[w][ct*16+lr] = q; }
    }
    __syncthreads();
    if(tid < 128){
        float S = lds_s[0][tid]+lds_s[1][tid]+lds_s[2][tid]+lds_s[3][tid];
        float Q = lds_q[0][tid]+lds_q[1][tid]+lds_q[2][tid]+lds_q[3][tid];
        bsum[bid*128 + tid] = S;
        bsq [bid*128 + tid] = Q;
    }
}

// ---- K2: finalize BN params (256 block partials, round-2 form)
__global__ __launch_bounds__(128) void k_bnfin(const float* __restrict__ bsum, const float* __restrict__ bsq,
                                               const float* __restrict__ gamma, const float* __restrict__ beta,
                                               float* __restrict__ bnA, float* __restrict__ bnB){
    int c = threadIdx.x;
    float S=0.f, Q=0.f;
    for(int b=0;b<256;b++){ S += bsum[b*128+c]; Q += bsq[b*128+c]; }
    float mu = S * (1.0f/16384.0f);
    float var = Q * (1.0f/16384.0f) - mu*mu;
    float A = gamma[c] * rsqrtf(var + 1e-5f);
    bnA[c] = A;
    bnB[c] = beta[c] - mu*A;
}

// ---- K3: BN+ReLU -> GEMM2 -> +b2 -> L2 normalize -> pair dots -> scaled bf16 (round-2 form)
__global__ __launch_bounds__(256) void k_gemm2(const float* __restrict__ h, const short* __restrict__ W2T,
                                               const float* __restrict__ bnA, const float* __restrict__ bnB,
                                               const float* __restrict__ b2,
                                               short* __restrict__ o1s, short* __restrict__ o2s,
                                               float* __restrict__ dvec){
    int bid = blockIdx.x;
    int tid = threadIdx.x;
    int w = tid >> 6, l = tid & 63, lr = l & 15, lk = l >> 4;
    int rowA = bid*64 + w*16 + lr;

    short8 a[4];
    const float* hp = h + rowA*128 + lk*8;
    #pragma unroll
    for(int c=0;c<4;c++){
        float4 h0 = *(const float4*)(hp + c*32);
        float4 h1 = *(const float4*)(hp + c*32 + 4);
        float4 A0 = *(const float4*)(bnA + c*32 + lk*8);
        float4 A1 = *(const float4*)(bnA + c*32 + lk*8 + 4);
        float4 B0 = *(const float4*)(bnB + c*32 + lk*8);
        float4 B1 = *(const float4*)(bnB + c*32 + lk*8 + 4);
        float4 v0, v1;
        v0.x = fmaxf(h0.x*A0.x + B0.x, 0.f); v0.y = fmaxf(h0.y*A0.y + B0.y, 0.f);
        v0.z = fmaxf(h0.z*A0.z + B0.z, 0.f); v0.w = fmaxf(h0.w*A0.w + B0.w, 0.f);
        v1.x = fmaxf(h1.x*A1.x + B1.x, 0.f); v1.y = fmaxf(h1.y*A1.y + B1.y, 0.f);
        v1.z = fmaxf(h1.z*A1.z + B1.z, 0.f); v1.w = fmaxf(h1.w*A1.w + B1.w, 0.f);
        a[c] = pack8(v0, v1);
    }

    f32x4 acc[8];
    #pragma unroll
    for(int ct=0; ct<8; ct++) acc[ct] = (f32x4){0.f,0.f,0.f,0.f};
    const short* wb = W2T + lr*128 + lk*8;
    #pragma unroll
    for(int c=0;c<4;c++){
        #pragma unroll
        for(int ct=0; ct<8; ct++){
            short8 b = *(const short8*)(wb + ct*16*128 + c*32);
            acc[ct] = __builtin_amdgcn_mfma_f32_16x16x32_bf16(a[c], b, acc[ct], 0,0,0);
        }
    }

    #pragma unroll
    for(int ct=0; ct<8; ct++){
        float bb = b2[ct*16 + lr];
        #pragma unroll
        for(int r=0;r<4;r++) acc[ct][r] += bb;
    }
    float n2[4] = {0.f,0.f,0.f,0.f};
    #pragma unroll
    for(int ct=0; ct<8; ct++){
        #pragma unroll
        for(int r=0;r<4;r++) n2[r] += acc[ct][r]*acc[ct][r];
    }
    #pragma unroll
    for(int r=0;r<4;r++){
        n2[r] += __shfl_xor(n2[r],1); n2[r] += __shfl_xor(n2[r],2);
        n2[r] += __shfl_xor(n2[r],4); n2[r] += __shfl_xor(n2[r],8);
    }
    float sc[4];
    #pragma unroll
    for(int r=0;r<4;r++) sc[r] = 1.0f / fmaxf(sqrtf(n2[r]), 1e-12f);
    #pragma unroll
    for(int ct=0; ct<8; ct++){
        #pragma unroll
        for(int r=0;r<4;r++) acc[ct][r] *= sc[r];
    }
    float dp0 = 0.f, dp1 = 0.f;
    #pragma unroll
    for(int ct=0; ct<8; ct++){
        dp0 += acc[ct][0]*acc[ct][1];
        dp1 += acc[ct][2]*acc[ct][3];
    }
    dp0 += __shfl_xor(dp0,1); dp0 += __shfl_xor(dp0,2); dp0 += __shfl_xor(dp0,4); dp0 += __shfl_xor(dp0,8);
    dp1 += __shfl_xor(dp1,1); dp1 += __shfl_xor(dp1,2); dp1 += __shfl_xor(dp1,4); dp1 += __shfl_xor(dp1,8);
    int r0 = bid*64 + w*16 + lk*4;
    if(lr==0){
        dvec[(r0>>1)    ] = dp0;
        dvec[(r0>>1) + 1] = dp1;
    }
    #pragma unroll
    for(int ct=0; ct<8; ct++){
        #pragma unroll
        for(int r=0;r<4;r++){
            int grow = r0 + r;
            int col  = ct*16 + lr;
            short bits = (short)f2bf(acc[ct][r] * OSCALE);
            if(grow & 1) o1s[(grow>>1)*128 + col] = bits;
            else         o2s[(grow>>1)*128 + col] = bits;
        }
    }
}

// ---- K4: fused similarity, compacted 1-D grid of 2112 working tiles.
//  bid <  1024           : pz=2 S12 full   (bx=bid&63, by=bid>>6), colsum always
//  bid >= 1024 (2x544)   : pz=0 S11 / pz=1 S22 upper-triangular tiles (by >= bx>>2)
//                          colsum only when by > bx>>2 (strictly upper)
//  rowsum partials -> r??p[by*8192 + row]; colsum partials -> c??p[bx*8192 + col]
__global__ __launch_bounds__(256) void k_sim(const short* __restrict__ o1s, const short* __restrict__ o2s,
                                             float* __restrict__ r11p, float* __restrict__ r22p,
                                             float* __restrict__ r12p, float* __restrict__ c11p,
                                             float* __restrict__ c22p, float* __restrict__ c12p){
    int bid = blockIdx.x;
    int pz, bx, by;
    if(bid < 1024){
        pz = 2; bx = bid & 63; by = bid >> 6;
    } else {
        int t = bid - 1024;                 // 0..1087
        pz = (t >= 544) ? 1 : 0;
        int rem = (t >= 544) ? t - 544 : t; // 0..543
        int bq = 0;
        while(rem >= 4*(16-bq)){ rem -= 4*(16-bq); bq++; }
        bx = 4*bq + (rem & 3);
        by = bq + (rem >> 2);
    }
    const short* A = (pz==1) ? o2s : o1s;
    const short* B = (pz==0) ? o1s : o2s;
    float* rowp = (pz==0) ? r11p : (pz==1 ? r22p : r12p);
    float* colp = (pz==0) ? c11p : (pz==1 ? c22p : c12p);
    const bool do_col = (pz==2) || (by > (bx>>2));

    int tid = threadIdx.x;
    int w = tid>>6, l = tid&63, lr = l&15, lk = l>>4;

    __shared__ __align__(16) short lds[2][8192];   // 32 KiB exactly -> 5 blocks/CU

    // A fragments: rows bx*128 + w*32 + rt*16 + lr
    short8 a[2][4];
    {
        const short* ap = A + (bx*128 + w*32 + lr)*128 + lk*8;
        #pragma unroll
        for(int rt=0;rt<2;rt++)
            #pragma unroll
            for(int c=0;c<4;c++)
                a[rt][c] = *(const short8*)(ap + rt*2048 + c*32);
    }

    // swizzled ds_read byte offsets per k-chunk c
    int sb[4];
    #pragma unroll
    for(int c=0;c<4;c++) sb[c] = lr*256 + ((((c*4+lk) ^ (lr&7)))<<4);

    // staging source pointers; col16 pre-swizzled so linear gload_lds dest gives
    // LDS[row][s] = B[row][s ^ (row&7)]
    const short* gsrc[4];
    #pragma unroll
    for(int i=0;i<4;i++){
        int row = (i*4 + w)*4 + (l>>4);
        int col16 = (l&15) ^ (row&7);
        gsrc[i] = B + (by*512 + row)*128 + col16*8;
    }

    // stage tile 0
    #pragma unroll
    for(int i=0;i<4;i++){
        __builtin_amdgcn_global_load_lds((as1_u32*)gsrc[i],
            (as3_u32*)(&lds[0][(i*4+w)*512]), 16, 0, 0);
        gsrc[i] += 8192;
    }
    asm volatile("s_waitcnt vmcnt(0)" ::: "memory");
    __syncthreads();

    float rs[2][4] = {{0.f,0.f,0.f,0.f},{0.f,0.f,0.f,0.f}};
    float cs8[8];
    const char* lbase = (const char*)&lds[0][0];

    #pragma unroll
    for(int t=0;t<8;t++){
        const int buf = t & 1;
        if(t<7){
            #pragma unroll
            for(int i=0;i<4;i++){
                __builtin_amdgcn_global_load_lds((as1_u32*)gsrc[i],
                    (as3_u32*)(&lds[buf^1][(i*4+w)*512]), 16, 0, 0);
                gsrc[i] += 8192;
            }
        }
        const char* lb = lbase + buf*16384;
        float cst = 0.f;
        #pragma unroll
        for(int jt=0;jt<4;jt++){
            short8 b0 = *(const short8*)(lb + jt*4096 + sb[0]);
            short8 b1 = *(const short8*)(lb + jt*4096 + sb[1]);
            short8 b2 = *(const short8*)(lb + jt*4096 + sb[2]);
            short8 b3 = *(const short8*)(lb + jt*4096 + sb[3]);
            f32x4 c0 = (f32x4){0.f,0.f,0.f,0.f};
            f32x4 c1 = (f32x4){0.f,0.f,0.f,0.f};
            c0 = __builtin_amdgcn_mfma_f32_16x16x32_bf16(a[0][0], b0, c0,0,0,0);
            c1 = __builtin_amdgcn_mfma_f32_16x16x32_bf16(a[1][0], b0, c1,0,0,0);
            c0 = __builtin_amdgcn_mfma_f32_16x16x32_bf16(a[0][1], b1, c0,0,0,0);
            c1 = __builtin_amdgcn_mfma_f32_16x16x32_bf16(a[1][1], b1, c1,0,0,0);
            c0 = __builtin_amdgcn_mfma_f32_16x16x32_bf16(a[0][2], b2, c0,0,0,0);
            c1 = __builtin_amdgcn_mfma_f32_16x16x32_bf16(a[1][2], b2, c1,0,0,0);
            c0 = __builtin_amdgcn_mfma_f32_16x16x32_bf16(a[0][3], b3, c0,0,0,0);
            c1 = __builtin_amdgcn_mfma_f32_16x16x32_bf16(a[1][3], b3, c1,0,0,0);
            float e00 = EXP2(c0[0]), e01 = EXP2(c0[1]), e02 = EXP2(c0[2]), e03 = EXP2(c0[3]);
            float e10 = EXP2(c1[0]), e11 = EXP2(c1[1]), e12 = EXP2(c1[2]), e13 = EXP2(c1[3]);
            rs[0][0]+=e00; rs[0][1]+=e01; rs[0][2]+=e02; rs[0][3]+=e03;
            rs[1][0]+=e10; rs[1][1]+=e11; rs[1][2]+=e12; rs[1][3]+=e13;
            if(do_col){
                float cv = ((e00+e01)+(e02+e03)) + ((e10+e11)+(e12+e13));
                cv += __shfl_xor(cv,16); cv += __shfl_xor(cv,32);
                if(jt == lk) cst = cv;    // lane keeps its j = t*64 + lk*16 + lr slice
            }
        }
        cs8[t] = cst;
        asm volatile("s_waitcnt vmcnt(0)" ::: "memory");
        __syncthreads();
    }

    // rowsum: reduce over 16 j-lanes, store per-split partial
    #pragma unroll
    for(int rt=0;rt<2;rt++){
        #pragma unroll
        for(int r=0;r<4;r++){
            rs[rt][r] += __shfl_xor(rs[rt][r],1);
            rs[rt][r] += __shfl_xor(rs[rt][r],2);
            rs[rt][r] += __shfl_xor(rs[rt][r],4);
            rs[rt][r] += __shfl_xor(rs[rt][r],8);
        }
        if(lr==0){
            float4 v; v.x=rs[rt][0]; v.y=rs[rt][1]; v.z=rs[rt][2]; v.w=rs[rt][3];
            *(float4*)(rowp + by*8192 + bx*128 + w*32 + rt*16 + lk*4) = v;
        }
    }

    // colsum epilogue: cross-wave reduce through (now dead) B-tile LDS
    if(do_col){
        float* lf = (float*)&lds[0][0];
        #pragma unroll
        for(int t=0;t<8;t++) lf[w*512 + t*64 + l] = cs8[t];   // j = t*64 + lk*16 + lr
        __syncthreads();
        int j0 = tid, j1 = tid + 256;
        float v0 = lf[j0] + lf[512+j0] + lf[1024+j0] + lf[1536+j0];
        float v1 = lf[j1] + lf[512+j1] + lf[1024+j1] + lf[1536+j1];
        colp[bx*8192 + by*512 + j0] = v0;
        colp[bx*8192 + by*512 + j1] = v1;
    }
}

// ---- K5: per-pair loss; reads exactly the written partial ranges
__global__ __launch_bounds__(256) void k_loss1(const float* __restrict__ r11, const float* __restrict__ r22,
                                               const float* __restrict__ r12, const float* __restrict__ c11,
                                               const float* __restrict__ c22, const float* __restrict__ c12,
                                               const float* __restrict__ dvec, float* __restrict__ lpart){
    int i = blockIdx.x*256 + threadIdx.x;
    int byi = i >> 9;                       // block-uniform (256 i's per block, 512 per chunk)
    float s11=0.f, s22=0.f, s12=0.f, s21=0.f;
    for(int by=byi; by<16; by++){ s11 += r11[by*8192+i]; s22 += r22[by*8192+i]; }
    for(int bx=0; bx<4*byi; bx++){ s11 += c11[bx*8192+i]; s22 += c22[bx*8192+i]; }
    #pragma unroll
    for(int s=0;s<16;s++) s12 += r12[s*8192+i];
    #pragma unroll
    for(int s=0;s<64;s++) s21 += c12[s*8192+i];
    float d1 = s11 - E2f + s12;
    float d2 = s22 - E2f + s21;
    float loss = 0.5f*(logf(d1)+logf(d2)) - 2.0f*dvec[i];
    loss += __shfl_xor(loss,1);  loss += __shfl_xor(loss,2);  loss += __shfl_xor(loss,4);
    loss += __shfl_xor(loss,8);  loss += __shfl_xor(loss,16); loss += __shfl_xor(loss,32);
    __shared__ float lds[4];
    if((threadIdx.x & 63) == 0) lds[threadIdx.x >> 6] = loss;
    __syncthreads();
    if(threadIdx.x == 0) lpart[blockIdx.x] = lds[0]+lds[1]+lds[2]+lds[3];
}

__global__ __launch_bounds__(64) void k_loss2(const float* __restrict__ lpart, float* __restrict__ out){
    if(threadIdx.x == 0){
        float s = 0.f;
        for(int i=0;i<32;i++) s += lpart[i];
        out[0] = s * (1.0f/8192.0f);
    }
}

extern "C" void kernel_launch(void* const* d_in, const int* in_sizes, int n_in,
                              void* d_out, int out_size, void* d_ws, size_t ws_size,
                              hipStream_t stream){
    (void)in_sizes; (void)n_in; (void)out_size; (void)ws_size;
    const float* doc   = (const float*)d_in[0];
    const float* W1    = (const float*)d_in[1];
    const float* b1    = (const float*)d_in[2];
    const float* gamma = (const float*)d_in[3];
    const float* beta  = (const float*)d_in[4];
    const float* W2    = (const float*)d_in[5];
    const float* b2    = (const float*)d_in[6];
    float* out = (float*)d_out;

    char* ws = (char*)d_ws;
    // [0, 8MB): h (live gemm1..gemm2), then reused by k_sim partials
    float* h     = (float*)(ws + 0);            // 16384*128*4 = 8388608
    float* c11p  = (float*)(ws + 0);            // 64*8192*4 = 2097152
    float* c22p  = (float*)(ws + 2097152);      // 2097152
    float* c12p  = (float*)(ws + 4194304);      // 2097152
    float* r11p  = (float*)(ws + 6291456);      // 16*8192*4 = 524288
    float* r22p  = (float*)(ws + 6815744);      // 524288
    float* r12p  = (float*)(ws + 7340032);      // 524288
    short* W1T   = (short*)(ws + 8388608);      // 131072
    short* W2T   = (short*)(ws + 8519680);      // 32768
    short* o1s   = (short*)(ws + 8552448);      // 2097152
    short* o2s   = (short*)(ws + 10649600);     // 2097152
    float* dvec  = (float*)(ws + 12746752);     // 32768
    float* bnA   = (float*)(ws + 12779520);     // 512
    float* bnB   = (float*)(ws + 12780032);     // 512
    float* bsum  = (float*)(ws + 12780544);     // 256*128*4 = 131072
    float* bsq   = (float*)(ws + 12911616);     // 131072
    float* lpart = (float*)(ws + 13042688);     // 128

    k_prep <<<320, 256, 0, stream>>>(W1, W2, W1T, W2T);
    k_gemm1<<<256, 256, 0, stream>>>(doc, b1, W1T, h, bsum, bsq);
    k_bnfin<<<1, 128, 0, stream>>>(bsum, bsq, gamma, beta, bnA, bnB);
    k_gemm2<<<256, 256, 0, stream>>>(h, W2T, bnA, bnB, b2, o1s, o2s, dvec);
    k_sim  <<<2112, 256, 0, stream>>>(o1s, o2s, r11p, r22p, r12p, c11p, c22p, c12p);
    k_loss1<<<32, 256, 0, stream>>>(r11p, r22p, r12p, c11p, c22p, c12p, dvec, lpart);
    k_loss2<<<1, 64, 0, stream>>>(lpart, out);
}

// Round 5
// 151.713 us; speedup vs baseline: 1.5447x; 1.4314x over previous
//
#include <hip/hip_runtime.h>

typedef __attribute__((ext_vector_type(8))) short short8;
typedef __attribute__((ext_vector_type(4))) float f32x4;

typedef const __attribute__((address_space(1))) unsigned int as1_u32;
typedef __attribute__((address_space(3))) unsigned int as3_u32;

#define E2f   7.38905609893065f     // exp(2)
#define OSCALE 1.69864357f          // sqrt(2*log2(e)) ; dot of scaled rows = 2*log2(e)*dot

#define EXP2(x) exp2f(x)

__device__ inline unsigned short f2bf(float f){
    union { float f; unsigned int u; } x; x.f = f;
    unsigned int u = x.u;
    return (unsigned short)((u + 0x7fffu + ((u >> 16) & 1u)) >> 16);
}

__device__ inline short8 pack8(float4 a, float4 b){
    short8 t;
    t[0]=(short)f2bf(a.x); t[1]=(short)f2bf(a.y); t[2]=(short)f2bf(a.z); t[3]=(short)f2bf(a.w);
    t[4]=(short)f2bf(b.x); t[5]=(short)f2bf(b.y); t[6]=(short)f2bf(b.z); t[7]=(short)f2bf(b.w);
    return t;
}

// ---- K0: cast+transpose W1 (512x128 -> 128x512 bf16) and W2 (128x128 -> 128x128 bf16)
__global__ __launch_bounds__(256) void k_prep(const float* __restrict__ W1, const float* __restrict__ W2,
                                              short* __restrict__ W1T, short* __restrict__ W2T){
    int idx = blockIdx.x*256 + threadIdx.x;
    if(idx < 512*128){
        int n = idx >> 9, k = idx & 511;
        W1T[idx] = (short)f2bf(W1[k*128 + n]);
    } else {
        int i2 = idx - 512*128;   // < 128*128
        int n = i2 >> 7, k = i2 & 127;
        W2T[i2] = (short)f2bf(W2[k*128 + n]);
    }
}

// ---- K1: h = doc @ W1 + b1 (bf16 MFMA), plus per-block BN partial sums
__global__ __launch_bounds__(256) void k_gemm1(const float* __restrict__ doc, const float* __restrict__ b1,
                                               const short* __restrict__ W1T, float* __restrict__ h,
                                               float* __restrict__ bsum, float* __restrict__ bsq){
    int bid = blockIdx.x;                   // 256 blocks, 64 rows each
    int tid = threadIdx.x;
    int w = tid >> 6, l = tid & 63, lr = l & 15, lk = l >> 4;
    int rowA = bid*64 + w*16 + lr;

    short8 a[16];
    const float* dp = doc + rowA*512 + lk*8;
    #pragma unroll
    for(int c=0;c<16;c++){
        float4 f0 = *(const float4*)(dp + c*32);
        float4 f1 = *(const float4*)(dp + c*32 + 4);
        a[c] = pack8(f0, f1);
    }

    f32x4 acc[8];
    #pragma unroll
    for(int ct=0; ct<8; ct++) acc[ct] = (f32x4){0.f,0.f,0.f,0.f};

    const short* wb = W1T + lr*512 + lk*8;
    #pragma unroll
    for(int c=0;c<16;c++){
        #pragma unroll
        for(int ct=0; ct<8; ct++){
            short8 b = *(const short8*)(wb + ct*16*512 + c*32);
            acc[ct] = __builtin_amdgcn_mfma_f32_16x16x32_bf16(a[c], b, acc[ct], 0,0,0);
        }
    }

    __shared__ float lds_s[4][128];
    __shared__ float lds_q[4][128];
    int rowD = bid*64 + w*16 + lk*4;
    #pragma unroll
    for(int ct=0; ct<8; ct++){
        float bb = b1[ct*16 + lr];
        float s = 0.f, q = 0.f;
        #pragma unroll
        for(int r=0;r<4;r++){
            float v = acc[ct][r] + bb;
            h[(rowD + r)*128 + ct*16 + lr] = v;
            s += v; q += v*v;
        }
        s += __shfl_xor(s,16); s += __shfl_xor(s,32);
        q += __shfl_xor(q,16); q += __shfl_xor(q,32);
        if(lk==0){ lds_s[w][ct*16+lr] = s; lds_q[w][ct*16+lr] = q; }
    }
    __syncthreads();
    if(tid < 128){
        float S = lds_s[0][tid]+lds_s[1][tid]+lds_s[2][tid]+lds_s[3][tid];
        float Q = lds_q[0][tid]+lds_q[1][tid]+lds_q[2][tid]+lds_q[3][tid];
        bsum[bid*128 + tid] = S;
        bsq [bid*128 + tid] = Q;
    }
}

// ---- K2: finalize BN params
__global__ __launch_bounds__(128) void k_bnfin(const float* __restrict__ bsum, const float* __restrict__ bsq,
                                               const float* __restrict__ gamma, const float* __restrict__ beta,
                                               float* __restrict__ bnA, float* __restrict__ bnB){
    int c = threadIdx.x;
    float S=0.f, Q=0.f;
    for(int b=0;b<256;b++){ S += bsum[b*128+c]; Q += bsq[b*128+c]; }
    float mu = S * (1.0f/16384.0f);
    float var = Q * (1.0f/16384.0f) - mu*mu;
    float A = gamma[c] * rsqrtf(var + 1e-5f);
    bnA[c] = A;
    bnB[c] = beta[c] - mu*A;
}

// ---- K3: BN+ReLU -> GEMM2 -> +b2 -> L2 normalize -> pair dots -> scaled bf16
__global__ __launch_bounds__(256) void k_gemm2(const float* __restrict__ h, const short* __restrict__ W2T,
                                               const float* __restrict__ bnA, const float* __restrict__ bnB,
                                               const float* __restrict__ b2,
                                               short* __restrict__ o1s, short* __restrict__ o2s,
                                               float* __restrict__ dvec){
    int bid = blockIdx.x;
    int tid = threadIdx.x;
    int w = tid >> 6, l = tid & 63, lr = l & 15, lk = l >> 4;
    int rowA = bid*64 + w*16 + lr;

    short8 a[4];
    const float* hp = h + rowA*128 + lk*8;
    #pragma unroll
    for(int c=0;c<4;c++){
        float4 h0 = *(const float4*)(hp + c*32);
        float4 h1 = *(const float4*)(hp + c*32 + 4);
        float4 A0 = *(const float4*)(bnA + c*32 + lk*8);
        float4 A1 = *(const float4*)(bnA + c*32 + lk*8 + 4);
        float4 B0 = *(const float4*)(bnB + c*32 + lk*8);
        float4 B1 = *(const float4*)(bnB + c*32 + lk*8 + 4);
        float4 v0, v1;
        v0.x = fmaxf(h0.x*A0.x + B0.x, 0.f); v0.y = fmaxf(h0.y*A0.y + B0.y, 0.f);
        v0.z = fmaxf(h0.z*A0.z + B0.z, 0.f); v0.w = fmaxf(h0.w*A0.w + B0.w, 0.f);
        v1.x = fmaxf(h1.x*A1.x + B1.x, 0.f); v1.y = fmaxf(h1.y*A1.y + B1.y, 0.f);
        v1.z = fmaxf(h1.z*A1.z + B1.z, 0.f); v1.w = fmaxf(h1.w*A1.w + B1.w, 0.f);
        a[c] = pack8(v0, v1);
    }

    f32x4 acc[8];
    #pragma unroll
    for(int ct=0; ct<8; ct++) acc[ct] = (f32x4){0.f,0.f,0.f,0.f};
    const short* wb = W2T + lr*128 + lk*8;
    #pragma unroll
    for(int c=0;c<4;c++){
        #pragma unroll
        for(int ct=0; ct<8; ct++){
            short8 b = *(const short8*)(wb + ct*16*128 + c*32);
            acc[ct] = __builtin_amdgcn_mfma_f32_16x16x32_bf16(a[c], b, acc[ct], 0,0,0);
        }
    }

    #pragma unroll
    for(int ct=0; ct<8; ct++){
        float bb = b2[ct*16 + lr];
        #pragma unroll
        for(int r=0;r<4;r++) acc[ct][r] += bb;
    }
    float n2[4] = {0.f,0.f,0.f,0.f};
    #pragma unroll
    for(int ct=0; ct<8; ct++){
        #pragma unroll
        for(int r=0;r<4;r++) n2[r] += acc[ct][r]*acc[ct][r];
    }
    #pragma unroll
    for(int r=0;r<4;r++){
        n2[r] += __shfl_xor(n2[r],1); n2[r] += __shfl_xor(n2[r],2);
        n2[r] += __shfl_xor(n2[r],4); n2[r] += __shfl_xor(n2[r],8);
    }
    float sc[4];
    #pragma unroll
    for(int r=0;r<4;r++) sc[r] = 1.0f / fmaxf(sqrtf(n2[r]), 1e-12f);
    #pragma unroll
    for(int ct=0; ct<8; ct++){
        #pragma unroll
        for(int r=0;r<4;r++) acc[ct][r] *= sc[r];
    }
    float dp0 = 0.f, dp1 = 0.f;
    #pragma unroll
    for(int ct=0; ct<8; ct++){
        dp0 += acc[ct][0]*acc[ct][1];
        dp1 += acc[ct][2]*acc[ct][3];
    }
    dp0 += __shfl_xor(dp0,1); dp0 += __shfl_xor(dp0,2); dp0 += __shfl_xor(dp0,4); dp0 += __shfl_xor(dp0,8);
    dp1 += __shfl_xor(dp1,1); dp1 += __shfl_xor(dp1,2); dp1 += __shfl_xor(dp1,4); dp1 += __shfl_xor(dp1,8);
    int r0 = bid*64 + w*16 + lk*4;
    if(lr==0){
        dvec[(r0>>1)    ] = dp0;
        dvec[(r0>>1) + 1] = dp1;
    }
    #pragma unroll
    for(int ct=0; ct<8; ct++){
        #pragma unroll
        for(int r=0;r<4;r++){
            int grow = r0 + r;
            int col  = ct*16 + lr;
            short bits = (short)f2bf(acc[ct][r] * OSCALE);
            if(grow & 1) o1s[(grow>>1)*128 + col] = bits;
            else         o2s[(grow>>1)*128 + col] = bits;
        }
    }
}

// ---- K4: fused similarity, compacted 1-D grid of 2112 working tiles.
//  bid <  1024           : pz=2 S12 full   (bx=bid&63, by=bid>>6), colsum always
//  bid >= 1024 (2x544)   : pz=0 S11 / pz=1 S22 upper-triangular tiles (by >= bx>>2)
//                          colsum only when by > bx>>2 (strictly upper)
// Inner loop/barrier/colsum mechanism = round-2 kernel verbatim (VGPR ~60).
__global__ __launch_bounds__(256) void k_sim(const short* __restrict__ o1s, const short* __restrict__ o2s,
                                             float* __restrict__ r11p, float* __restrict__ r22p,
                                             float* __restrict__ r12p, float* __restrict__ c11p,
                                             float* __restrict__ c22p, float* __restrict__ c12p){
    int bid = blockIdx.x;
    int pz, bx, by;
    if(bid < 1024){
        pz = 2; bx = bid & 63; by = bid >> 6;
    } else {
        int t = bid - 1024;                 // 0..1087
        pz = (t >= 544) ? 1 : 0;
        int rem = (t >= 544) ? t - 544 : t; // 0..543
        int bq = 0;
        while(rem >= 4*(16-bq)){ rem -= 4*(16-bq); bq++; }
        bx = 4*bq + (rem & 3);
        by = bq + (rem >> 2);
    }
    const short* A = (pz==1) ? o2s : o1s;
    const short* B = (pz==0) ? o1s : o2s;
    float* rowp = (pz==0) ? r11p : (pz==1 ? r22p : r12p);
    float* colp = (pz==0) ? c11p : (pz==1 ? c22p : c12p);
    const bool do_col = (pz==2) || (by > (bx>>2));

    int tid = threadIdx.x;
    int w = tid>>6, l = tid&63, lr = l&15, lk = l>>4;

    __shared__ __align__(16) short lds[2][8192];   // 2 x 64 rows x 128 bf16
    __shared__ float cs_lds[2][4][64];

    // A fragments: rows bx*128 + w*32 + rt*16 + lr
    short8 a[2][4];
    {
        const short* ap = A + (bx*128 + w*32 + lr)*128 + lk*8;
        #pragma unroll
        for(int rt=0;rt<2;rt++)
            #pragma unroll
            for(int c=0;c<4;c++)
                a[rt][c] = *(const short8*)(ap + rt*2048 + c*32);
    }

    // swizzled ds_read byte offsets per k-chunk c
    int sb[4];
    #pragma unroll
    for(int c=0;c<4;c++) sb[c] = lr*256 + ((((c*4+lk) ^ (lr&7)))<<4);

    // staging source pointers; col16 pre-swizzled so linear gload_lds dest gives
    // LDS[row][s] = B[row][s ^ (row&7)]
    const short* gsrc[4];
    #pragma unroll
    for(int i=0;i<4;i++){
        int chunk = i*4 + w;              // 1KB chunk = 4 rows
        int row = chunk*4 + (l>>4);
        int col16 = (l&15) ^ (row&7);
        gsrc[i] = B + (by*512 + row)*128 + col16*8;
    }

    // stage tile 0
    #pragma unroll
    for(int i=0;i<4;i++){
        __builtin_amdgcn_global_load_lds((as1_u32*)gsrc[i],
            (as3_u32*)(&lds[0][(i*4+w)*512]), 16, 0, 0);
        gsrc[i] += 8192;   // next 64-row tile
    }
    asm volatile("s_waitcnt vmcnt(0)" ::: "memory");
    __syncthreads();

    float rs[2][4] = {{0.f,0.f,0.f,0.f},{0.f,0.f,0.f,0.f}};
    int buf = 0;
    const char* lbase = (const char*)&lds[0][0];

    for(int t=0;t<8;t++){
        if(t<7){
            #pragma unroll
            for(int i=0;i<4;i++){
                __builtin_amdgcn_global_load_lds((as1_u32*)gsrc[i],
                    (as3_u32*)(&lds[buf^1][(i*4+w)*512]), 16, 0, 0);
                gsrc[i] += 8192;
            }
        }
        const char* lb = lbase + buf*16384;
        #pragma unroll
        for(int jt=0;jt<4;jt++){
            short8 b0 = *(const short8*)(lb + jt*4096 + sb[0]);
            short8 b1 = *(const short8*)(lb + jt*4096 + sb[1]);
            short8 b2 = *(const short8*)(lb + jt*4096 + sb[2]);
            short8 b3 = *(const short8*)(lb + jt*4096 + sb[3]);
            f32x4 c0 = (f32x4){0.f,0.f,0.f,0.f};
            f32x4 c1 = (f32x4){0.f,0.f,0.f,0.f};
            c0 = __builtin_amdgcn_mfma_f32_16x16x32_bf16(a[0][0], b0, c0,0,0,0);
            c1 = __builtin_amdgcn_mfma_f32_16x16x32_bf16(a[1][0], b0, c1,0,0,0);
            c0 = __builtin_amdgcn_mfma_f32_16x16x32_bf16(a[0][1], b1, c0,0,0,0);
            c1 = __builtin_amdgcn_mfma_f32_16x16x32_bf16(a[1][1], b1, c1,0,0,0);
            c0 = __builtin_amdgcn_mfma_f32_16x16x32_bf16(a[0][2], b2, c0,0,0,0);
            c1 = __builtin_amdgcn_mfma_f32_16x16x32_bf16(a[1][2], b2, c1,0,0,0);
            c0 = __builtin_amdgcn_mfma_f32_16x16x32_bf16(a[0][3], b3, c0,0,0,0);
            c1 = __builtin_amdgcn_mfma_f32_16x16x32_bf16(a[1][3], b3, c1,0,0,0);
            float e00 = EXP2(c0[0]), e01 = EXP2(c0[1]), e02 = EXP2(c0[2]), e03 = EXP2(c0[3]);
            float e10 = EXP2(c1[0]), e11 = EXP2(c1[1]), e12 = EXP2(c1[2]), e13 = EXP2(c1[3]);
            rs[0][0]+=e00; rs[0][1]+=e01; rs[0][2]+=e02; rs[0][3]+=e03;
            rs[1][0]+=e10; rs[1][1]+=e11; rs[1][2]+=e12; rs[1][3]+=e13;
            if(do_col){
                float cv = ((e00+e01)+(e02+e03)) + ((e10+e11)+(e12+e13));
                cv += __shfl_xor(cv,16); cv += __shfl_xor(cv,32);
                if(lk==0) cs_lds[t&1][w][jt*16+lr] = cv;
            }
        }
        asm volatile("s_waitcnt vmcnt(0)" ::: "memory");
        __syncthreads();
        if(do_col && tid < 64){
            float v = cs_lds[t&1][0][tid]+cs_lds[t&1][1][tid]
                    + cs_lds[t&1][2][tid]+cs_lds[t&1][3][tid];
            colp[bx*8192 + by*512 + t*64 + tid] = v;
        }
        buf ^= 1;
    }

    // rowsum: reduce over the 16 j-lanes, store per-split partial
    #pragma unroll
    for(int rt=0;rt<2;rt++){
        #pragma unroll
        for(int r=0;r<4;r++){
            rs[rt][r] += __shfl_xor(rs[rt][r],1);
            rs[rt][r] += __shfl_xor(rs[rt][r],2);
            rs[rt][r] += __shfl_xor(rs[rt][r],4);
            rs[rt][r] += __shfl_xor(rs[rt][r],8);
        }
        if(lr==0){
            float4 v; v.x=rs[rt][0]; v.y=rs[rt][1]; v.z=rs[rt][2]; v.w=rs[rt][3];
            *(float4*)(rowp + by*8192 + bx*128 + w*32 + rt*16 + lk*4) = v;
        }
    }
}

// ---- K5: per-pair loss; reads exactly the written partial ranges
__global__ __launch_bounds__(256) void k_loss1(const float* __restrict__ r11, const float* __restrict__ r22,
                                               const float* __restrict__ r12, const float* __restrict__ c11,
                                               const float* __restrict__ c22, const float* __restrict__ c12,
                                               const float* __restrict__ dvec, float* __restrict__ lpart){
    int i = blockIdx.x*256 + threadIdx.x;
    int byi = i >> 9;                       // block-uniform (256 i's per block, 512 per chunk)
    float s11=0.f, s22=0.f, s12=0.f, s21=0.f;
    for(int by=byi; by<16; by++){ s11 += r11[by*8192+i]; s22 += r22[by*8192+i]; }
    for(int bx=0; bx<4*byi; bx++){ s11 += c11[bx*8192+i]; s22 += c22[bx*8192+i]; }
    #pragma unroll
    for(int s=0;s<16;s++) s12 += r12[s*8192+i];
    #pragma unroll
    for(int s=0;s<64;s++) s21 += c12[s*8192+i];
    float d1 = s11 - E2f + s12;
    float d2 = s22 - E2f + s21;
    float loss = 0.5f*(logf(d1)+logf(d2)) - 2.0f*dvec[i];
    loss += __shfl_xor(loss,1);  loss += __shfl_xor(loss,2);  loss += __shfl_xor(loss,4);
    loss += __shfl_xor(loss,8);  loss += __shfl_xor(loss,16); loss += __shfl_xor(loss,32);
    __shared__ float lds[4];
    if((threadIdx.x & 63) == 0) lds[threadIdx.x >> 6] = loss;
    __syncthreads();
    if(threadIdx.x == 0) lpart[blockIdx.x] = lds[0]+lds[1]+lds[2]+lds[3];
}

__global__ __launch_bounds__(64) void k_loss2(const float* __restrict__ lpart, float* __restrict__ out){
    if(threadIdx.x == 0){
        float s = 0.f;
        for(int i=0;i<32;i++) s += lpart[i];
        out[0] = s * (1.0f/8192.0f);
    }
}

extern "C" void kernel_launch(void* const* d_in, const int* in_sizes, int n_in,
                              void* d_out, int out_size, void* d_ws, size_t ws_size,
                              hipStream_t stream){
    (void)in_sizes; (void)n_in; (void)out_size; (void)ws_size;
    const float* doc   = (const float*)d_in[0];
    const float* W1    = (const float*)d_in[1];
    const float* b1    = (const float*)d_in[2];
    const float* gamma = (const float*)d_in[3];
    const float* beta  = (const float*)d_in[4];
    const float* W2    = (const float*)d_in[5];
    const float* b2    = (const float*)d_in[6];
    float* out = (float*)d_out;

    char* ws = (char*)d_ws;
    // [0, 8MB): h (live gemm1..gemm2), then reused by k_sim partials
    float* h     = (float*)(ws + 0);            // 16384*128*4 = 8388608
    float* c11p  = (float*)(ws + 0);            // 64*8192*4 = 2097152
    float* c22p  = (float*)(ws + 2097152);      // 2097152
    float* c12p  = (float*)(ws + 4194304);      // 2097152
    float* r11p  = (float*)(ws + 6291456);      // 16*8192*4 = 524288
    float* r22p  = (float*)(ws + 6815744);      // 524288
    float* r12p  = (float*)(ws + 7340032);      // 524288
    short* W1T   = (short*)(ws + 8388608);      // 131072
    short* W2T   = (short*)(ws + 8519680);      // 32768
    short* o1s   = (short*)(ws + 8552448);      // 2097152
    short* o2s   = (short*)(ws + 10649600);     // 2097152
    float* dvec  = (float*)(ws + 12746752);     // 32768
    float* bnA   = (float*)(ws + 12779520);     // 512
    float* bnB   = (float*)(ws + 12780032);     // 512
    float* bsum  = (float*)(ws + 12780544);     // 256*128*4 = 131072
    float* bsq   = (float*)(ws + 12911616);     // 131072
    float* lpart = (float*)(ws + 13042688);     // 128

    k_prep <<<320, 256, 0, stream>>>(W1, W2, W1T, W2T);
    k_gemm1<<<256, 256, 0, stream>>>(doc, b1, W1T, h, bsum, bsq);
    k_bnfin<<<1, 128, 0, stream>>>(bsum, bsq, gamma, beta, bnA, bnB);
    k_gemm2<<<256, 256, 0, stream>>>(h, W2T, bnA, bnB, b2, o1s, o2s, dvec);
    k_sim  <<<2112, 256, 0, stream>>>(o1s, o2s, r11p, r22p, r12p, c11p, c22p, c12p);
    k_loss1<<<32, 256, 0, stream>>>(r11p, r22p, r12p, c11p, c22p, c12p, dvec, lpart);
    k_loss2<<<1, 64, 0, stream>>>(lpart, out);
}